// Round 3
// baseline (417.334 us; speedup 1.0000x reference)
//
#include <hip/hip_runtime.h>
#include <math.h>

#define NNODE 65536
#define NEDGE 1048576
#define NGRAPH 128
#define NPG 512
#define EPG 8192

// ---- CSR build (block per graph) + init: alive, gate, dinv(layer1), score_acc=0 ----

__global__ __launch_bounds__(512) void k_csr(const int* __restrict__ srcE, const int* __restrict__ dstE,
                                             int* __restrict__ rp, int* __restrict__ csr,
                                             float* __restrict__ gate, int* __restrict__ alive,
                                             float* __restrict__ dinv, float* __restrict__ score_acc) {
    __shared__ int cnt[512];
    __shared__ int tmp[512];
    int g = blockIdx.x, t = threadIdx.x;
    int nd = g * NPG + t;
    cnt[t] = 0;
    gate[nd] = 1.f;
    alive[nd] = nd;
    score_acc[nd] = 0.f;
    __syncthreads();
    int ebase = g * EPG;
    int dl[16];
    for (int i = 0; i < 16; ++i) {
        int e = ebase + t + i * 512;
        int d = dstE[e] - g * NPG;
        dl[i] = d;
        atomicAdd(&cnt[d], 1);
    }
    __syncthreads();
    int v = cnt[t], incl = v;
    dinv[nd] = rsqrtf(1.f + (float)v);   // layer-1: all masks = 1
    for (int off = 1; off < 512; off <<= 1) {
        tmp[t] = incl; __syncthreads();
        if (t >= off) incl += tmp[t - off];
        __syncthreads();
    }
    int excl = incl - v;
    rp[nd] = ebase + excl;
    if (g == NGRAPH - 1 && t == 511) rp[NNODE] = NEDGE;
    __syncthreads();
    cnt[t] = excl;
    __syncthreads();
    for (int i = 0; i < 16; ++i) {
        int e = ebase + t + i * 512;
        int pos = atomicAdd(&cnt[dl[i]], 1);
        csr[ebase + pos] = srcE[e];
    }
}

// ---------------- h[alive rows] = (x * gate) @ W ----------------

#define ACC4(A, X, W0, W1) \
    A.x = fmaf(X.x, W0.x, A.x); A.x = fmaf(X.y, W1.x, A.x); \
    A.y = fmaf(X.x, W0.y, A.y); A.y = fmaf(X.y, W1.y, A.y); \
    A.z = fmaf(X.x, W0.z, A.z); A.z = fmaf(X.y, W1.z, A.z); \
    A.w = fmaf(X.x, W0.w, A.w); A.w = fmaf(X.y, W1.w, A.w);

__global__ __launch_bounds__(256) void k_gemm(const float* __restrict__ x, const float* __restrict__ W,
                                              const float* __restrict__ gate, const int* __restrict__ alive,
                                              float* __restrict__ h) {
    __shared__ float xs[64 * 128];
    __shared__ float ws[64 * 64];
    int t = threadIdx.x;
    int rowbase = blockIdx.x * 64;
    int colbase = blockIdx.y * 64;

    for (int p = 0; p < 8; ++p) {
        int i = t + p * 256;
        int r = i >> 5, q = i & 31;
        int nd = alive[rowbase + r];
        float g = gate[nd];
        float4 v = *(const float4*)(x + (size_t)nd * 128 + q * 4);
        v.x *= g; v.y *= g; v.z *= g; v.w *= g;
        *(float4*)(xs + r * 128 + q * 4) = v;
    }

    int c4 = (t & 15) * 4;
    int rb = (t >> 4) * 4;
    float4 a0 = {0, 0, 0, 0}, a1 = a0, a2 = a0, a3 = a0;

    for (int kh = 0; kh < 2; ++kh) {
        if (kh) __syncthreads();
        for (int p = 0; p < 4; ++p) {
            int i = t + p * 256;
            int kk = i >> 4, q = i & 15;
            *(float4*)(ws + kk * 64 + q * 4) =
                *(const float4*)(W + (size_t)(kh * 64 + kk) * 128 + colbase + q * 4);
        }
        __syncthreads();
        int kb = kh * 64;
        for (int k = 0; k < 64; k += 2) {
            float4 w0 = *(const float4*)(ws + k * 64 + c4);
            float4 w1 = *(const float4*)(ws + (k + 1) * 64 + c4);
            float2 x0 = *(const float2*)(xs + (rb + 0) * 128 + kb + k);
            float2 x1 = *(const float2*)(xs + (rb + 1) * 128 + kb + k);
            float2 x2 = *(const float2*)(xs + (rb + 2) * 128 + kb + k);
            float2 x3 = *(const float2*)(xs + (rb + 3) * 128 + kb + k);
            ACC4(a0, x0, w0, w1); ACC4(a1, x1, w0, w1);
            ACC4(a2, x2, w0, w1); ACC4(a3, x3, w0, w1);
        }
    }

    int n0 = alive[rowbase + rb + 0];
    int n1 = alive[rowbase + rb + 1];
    int n2 = alive[rowbase + rb + 2];
    int n3 = alive[rowbase + rb + 3];
    *(float4*)(h + (size_t)n0 * 128 + colbase + c4) = a0;
    *(float4*)(h + (size_t)n1 * 128 + colbase + c4) = a1;
    *(float4*)(h + (size_t)n2 * 128 + colbase + c4) = a2;
    *(float4*)(h + (size_t)n3 * 128 + colbase + c4) = a3;
}

// ---------------- LDS-staged agg + relu + partial score ----------------
// Block = (graph g, feature-quarter fq). Stages h[512][32] + dinv[512] in LDS;
// gather is pure LDS. Neighbor ids: one 16-lane vector load per dst + __shfl broadcast.
// blockIdx: b&127 = graph -> all 4 fq blocks of a graph land on the same XCD (b%8 preserved).

__global__ __launch_bounds__(256) void k_agg(const float* __restrict__ h, const float* __restrict__ dinv,
                                             const int* __restrict__ rp, const int* __restrict__ csr,
                                             const int* __restrict__ alive, const float* __restrict__ bias,
                                             const float* __restrict__ p, float* __restrict__ out,
                                             float* __restrict__ score_acc, int nA, int Kp) {
    __shared__ float hs[512 * 32];   // 64 KB
    __shared__ float dv[512];
    __shared__ int dloc[512];
    __shared__ int djb[512];
    __shared__ int ddeg[512];
    int t = threadIdx.x;
    int g = blockIdx.x & 127;
    int fq = blockIdx.x >> 7;
    int gbase = g * NPG;
    const float* hb = h + (size_t)gbase * 128 + fq * 32;

    for (int it = 0; it < 16; ++it) {
        int i = t + it * 256;
        int n = i >> 3, q = i & 7;
        float4 v = *(const float4*)(hb + (size_t)n * 128 + q * 4);
        *(float4*)(&hs[n * 32 + q * 4]) = v;
    }
    for (int n = t; n < NPG; n += 256) dv[n] = dinv[gbase + n];
    for (int i = t; i < nA; i += 256) {
        int d = alive[g * Kp + i];
        dloc[i] = d - gbase;
        int jb = rp[d];
        djb[i] = jb;
        ddeg[i] = rp[d + 1] - jb;
    }
    __syncthreads();

    int lane = t & 63;
    int w = t >> 6;
    int slot = lane >> 4;
    int f16 = lane & 15;
    int f2 = f16 * 2;
    int base = lane & 48;
    float2 b2 = *(const float2*)(bias + fq * 32 + f2);
    float2 pv = *(const float2*)(p + fq * 32 + f2);

    int iters = nA >> 4;   // nA in {512,256,128} -> multiple of 16
    for (int it = 0; it < iters; ++it) {
        int i = it * 16 + w * 4 + slot;
        int dl = dloc[i];
        int jb = djb[i];
        int deg = ddeg[i];
        float dvd = dv[dl];
        float2 hd = *(const float2*)(&hs[dl * 32 + f2]);
        float accx = dvd * hd.x, accy = dvd * hd.y;

        int sv = 0;
        if (f16 < deg) sv = csr[jb + f16];
        int dmin = deg < 16 ? deg : 16;
        for (int j = 0; j < dmin; ++j) {
            int s = __shfl(sv, base + j);
            int sl = s - gbase;
            float wgt = dv[sl];
            float2 hv = *(const float2*)(&hs[sl * 32 + f2]);
            accx = fmaf(wgt, hv.x, accx);
            accy = fmaf(wgt, hv.y, accy);
        }
        for (int j = 16; j < deg; ++j) {          // rare tail
            int s = csr[jb + j];
            int sl = s - gbase;
            float wgt = dv[sl];
            float2 hv = *(const float2*)(&hs[sl * 32 + f2]);
            accx = fmaf(wgt, hv.x, accx);
            accy = fmaf(wgt, hv.y, accy);
        }

        float ox = fmaxf(fmaf(dvd, accx, b2.x), 0.f);
        float oy = fmaxf(fmaf(dvd, accy, b2.y), 0.f);
        int d = gbase + dl;
        float2 o; o.x = ox; o.y = oy;
        *(float2*)(out + (size_t)d * 128 + fq * 32 + f2) = o;

        float ps = fmaf(ox, pv.x, oy * pv.y);
        ps += __shfl_xor(ps, 1);
        ps += __shfl_xor(ps, 2);
        ps += __shfl_xor(ps, 4);
        ps += __shfl_xor(ps, 8);
        if (f16 == 0) atomicAdd(&score_acc[d], ps);
    }
}

// ---------------- fused: score finalize + top-k + readout + next-layer dinv ----------------

__global__ __launch_bounds__(512) void k_pool(const float* __restrict__ xb, float* __restrict__ score_acc,
                                              const float* __restrict__ pvec, float* __restrict__ gate,
                                              int* __restrict__ alive, float* __restrict__ hg,
                                              const int* __restrict__ rp, const int* __restrict__ csr,
                                              float* __restrict__ dinv, int K, int last) {
    __shared__ float s[512];
    __shared__ int ad[256];
    __shared__ float ag[256];
    __shared__ float red[1024];
    __shared__ int m_new[512];
    __shared__ int scnt;
    int t = threadIdx.x, g = blockIdx.x;
    int gbase = g * NPG;
    int d = gbase + t;

    // ||p||^2 reduce
    red[t] = (t < 128) ? pvec[t] * pvec[t] : 0.f;
    if (t == 0) scnt = 0;
    __syncthreads();
    for (int off = 256; off >= 1; off >>= 1) {
        if (t < off) red[t] += red[t + off];
        __syncthreads();
    }
    float rn = rsqrtf(red[0]);
    __syncthreads();

    float odv = dinv[d];
    int m = odv > 0.f;
    float sc = 1.f / (1.f + expf(-score_acc[d] * rn));
    s[t] = m ? sc : -__builtin_inff();
    __syncthreads();
    for (int k2 = 2; k2 <= 512; k2 <<= 1)
        for (int j = k2 >> 1; j > 0; j >>= 1) {
            int ixj = t ^ j;
            if (ixj > t) {
                float a = s[t], bv = s[ixj];
                bool sw = ((t & k2) == 0) ? (a < bv) : (a > bv);
                if (sw) { s[t] = bv; s[ixj] = a; }
            }
            __syncthreads();
        }
    float thr = s[K - 1];
    int nm = (m && sc >= thr) ? 1 : 0;
    gate[d] = nm ? sc : 0.f;
    m_new[t] = nm;
    if (nm) {
        int pos = atomicAdd(&scnt, 1);
        if (pos < K) {
            alive[g * K + pos] = d;
            ad[pos] = d;
            ag[pos] = sc;
        }
    }
    __syncthreads();

    if (!last) {
        // next-layer dinv from new mask (neighbors are intra-graph -> m_new in LDS)
        float nd = 0.f;
        if (nm) {
            int jb = rp[d], je = rp[d + 1];
            int sum = 0;
            for (int j = jb; j < je; ++j) sum += m_new[csr[j] - gbase];
            nd = rsqrtf(1.f + (float)sum);
        }
        dinv[d] = nd;
        score_acc[d] = 0.f;
    }

    // readout on new alive set (values >= 0, outer relu identity); 4x unrolled gather
    int f = t & 127, c = t >> 7;
    float mx = 0.f, sm = 0.f;
    for (int j = c; j < K; j += 16) {
        float v0 = xb[(size_t)ad[j] * 128 + f] * ag[j];
        float v1 = xb[(size_t)ad[j + 4] * 128 + f] * ag[j + 4];
        float v2 = xb[(size_t)ad[j + 8] * 128 + f] * ag[j + 8];
        float v3 = xb[(size_t)ad[j + 12] * 128 + f] * ag[j + 12];
        mx = fmaxf(fmaxf(fmaxf(mx, v0), fmaxf(v1, v2)), v3);
        sm += v0 + v1 + v2 + v3;
    }
    red[t] = mx; red[512 + t] = sm;
    __syncthreads();
    if (c == 0) {
        for (int cc = 1; cc < 4; ++cc) {
            mx = fmaxf(mx, red[cc * 128 + f]);
            sm += red[512 + cc * 128 + f];
        }
        hg[g * 256 + f] += mx;
        hg[g * 256 + 128 + f] += sm / (float)K;
    }
}

// ---------------- fused MLP head ----------------

__global__ __launch_bounds__(256) void k_mlp(const float* __restrict__ inp_c, const float* __restrict__ hg,
                                             const float* __restrict__ We, const float* __restrict__ Wa,
                                             const float* __restrict__ ba, const float* __restrict__ Wb,
                                             const float* __restrict__ bb, const float* __restrict__ Wc,
                                             float* __restrict__ out) {
    __shared__ float fus[320];
    __shared__ float h1[256];
    __shared__ float h2[128];
    int t = threadIdx.x, g = blockIdx.x;
    if (t < 64) {
        float a = 0.f;
        for (int j = 0; j < 64; ++j) a = fmaf(inp_c[g * 64 + j], We[j * 64 + t], a);
        fus[t] = fmaxf(a, 0.f);
    }
    fus[64 + t] = hg[g * 256 + t];
    __syncthreads();
    {
        float a = ba[t];
        for (int j = 0; j < 320; ++j) a = fmaf(fus[j], Wa[j * 256 + t], a);
        h1[t] = fmaxf(a, 0.f);
    }
    __syncthreads();
    if (t < 128) {
        float a = bb[t];
        for (int j = 0; j < 256; ++j) a = fmaf(h1[j], Wb[j * 128 + t], a);
        h2[t] = fmaxf(a, 0.f);
    }
    __syncthreads();
    if (t == 0) {
        float a = 0.f;
        for (int j = 0; j < 128; ++j) a = fmaf(h2[j], Wc[j], a);
        out[g] = a;
    }
}

// ---------------- launch ----------------

extern "C" void kernel_launch(void* const* d_in, const int* in_sizes, int n_in,
                              void* d_out, int out_size, void* d_ws, size_t ws_size,
                              hipStream_t stream) {
    (void)in_sizes; (void)n_in; (void)out_size; (void)ws_size;
    const float* x_in  = (const float*)d_in[0];
    const float* inp_c = (const float*)d_in[1];
    const int*   ei    = (const int*)d_in[2];
    const int* srcE = ei;
    const int* dstE = ei + NEDGE;
    const float* Wl[3] = {(const float*)d_in[4], (const float*)d_in[6], (const float*)d_in[8]};
    const float* bl[3] = {(const float*)d_in[5], (const float*)d_in[7], (const float*)d_in[9]};
    const float* Pl[3] = {(const float*)d_in[10], (const float*)d_in[11], (const float*)d_in[12]};
    const float* We = (const float*)d_in[13];
    const float* Wa = (const float*)d_in[14];
    const float* ba = (const float*)d_in[15];
    const float* Wb = (const float*)d_in[16];
    const float* bb = (const float*)d_in[17];
    const float* Wc = (const float*)d_in[18];
    float* out = (float*)d_out;

    char* w = (char*)d_ws;
    size_t off = 0;
    auto alloc = [&](size_t bytes) -> void* {
        void* p = w + off;
        off = (off + bytes + 255) & ~(size_t)255;
        return p;
    };
    int*   rp    = (int*)alloc((NNODE + 1) * 4);
    int*   csr   = (int*)alloc(NEDGE * 4);
    float* dinv  = (float*)alloc(NNODE * 4);
    float* gate  = (float*)alloc(NNODE * 4);
    float* sacc  = (float*)alloc(NNODE * 4);
    int*   alive = (int*)alloc(NNODE * 4);
    float* hbuf  = (float*)alloc((size_t)NNODE * 128 * 4);
    float* xbuf  = (float*)alloc((size_t)NNODE * 128 * 4);
    float* hg    = (float*)alloc(NGRAPH * 256 * 4);

    hipMemsetAsync(hg, 0, NGRAPH * 256 * 4, stream);
    k_csr<<<NGRAPH, 512, 0, stream>>>(srcE, dstE, rp, csr, gate, alive, dinv, sacc);

    const int rows_in[3] = {65536, 32768, 16384};
    const int Ks[3] = {256, 128, 64};
    const int Kp[3] = {512, 256, 128};   // alive-list stride entering layer l
    for (int l = 0; l < 3; ++l) {
        const float* xin = (l == 0) ? x_in : xbuf;
        k_gemm<<<dim3(rows_in[l] / 64, 2), 256, 0, stream>>>(xin, Wl[l], gate, alive, hbuf);
        k_agg<<<512, 256, 0, stream>>>(hbuf, dinv, rp, csr, alive, bl[l], Pl[l],
                                       xbuf, sacc, rows_in[l] / NGRAPH, Kp[l]);
        k_pool<<<NGRAPH, 512, 0, stream>>>(xbuf, sacc, Pl[l], gate, alive, hg,
                                           rp, csr, dinv, Ks[l], l == 2);
    }
    k_mlp<<<NGRAPH, 256, 0, stream>>>(inp_c, hg, We, Wa, ba, Wb, bb, Wc, out);
}

// Round 4
// 342.882 us; speedup vs baseline: 1.2171x; 1.2171x over previous
//
#include <hip/hip_runtime.h>
#include <math.h>

#define NNODE 65536
#define NEDGE 1048576
#define NGRAPH 128
#define NPG 512
#define EPG 8192

// ---- CSR build (block per graph) + init: alive, gate, dinv(layer1) ----

__global__ __launch_bounds__(512) void k_csr(const int* __restrict__ srcE, const int* __restrict__ dstE,
                                             int* __restrict__ rp, int* __restrict__ csr,
                                             float* __restrict__ gate, int* __restrict__ alive,
                                             float* __restrict__ dinv) {
    __shared__ int cnt[512];
    __shared__ int tmp[512];
    int g = blockIdx.x, t = threadIdx.x;
    int nd = g * NPG + t;
    cnt[t] = 0;
    gate[nd] = 1.f;
    alive[nd] = nd;
    __syncthreads();
    int ebase = g * EPG;
    int dl[16];
    for (int i = 0; i < 16; ++i) {
        int e = ebase + t + i * 512;
        int d = dstE[e] - g * NPG;
        dl[i] = d;
        atomicAdd(&cnt[d], 1);
    }
    __syncthreads();
    int v = cnt[t], incl = v;
    dinv[nd] = rsqrtf(1.f + (float)v);   // layer-1: all masks = 1
    for (int off = 1; off < 512; off <<= 1) {
        tmp[t] = incl; __syncthreads();
        if (t >= off) incl += tmp[t - off];
        __syncthreads();
    }
    int excl = incl - v;
    rp[nd] = ebase + excl;
    if (g == NGRAPH - 1 && t == 511) rp[NNODE] = NEDGE;
    __syncthreads();
    cnt[t] = excl;
    __syncthreads();
    for (int i = 0; i < 16; ++i) {
        int e = ebase + t + i * 512;
        int pos = atomicAdd(&cnt[dl[i]], 1);
        csr[ebase + pos] = srcE[e];
    }
}

// ---------------- h[alive rows] = (x * gate) @ W ----------------

#define ACC4(A, X, W0, W1) \
    A.x = fmaf(X.x, W0.x, A.x); A.x = fmaf(X.y, W1.x, A.x); \
    A.y = fmaf(X.x, W0.y, A.y); A.y = fmaf(X.y, W1.y, A.y); \
    A.z = fmaf(X.x, W0.z, A.z); A.z = fmaf(X.y, W1.z, A.z); \
    A.w = fmaf(X.x, W0.w, A.w); A.w = fmaf(X.y, W1.w, A.w);

__global__ __launch_bounds__(256) void k_gemm(const float* __restrict__ x, const float* __restrict__ W,
                                              const float* __restrict__ gate, const int* __restrict__ alive,
                                              float* __restrict__ h) {
    __shared__ float xs[64 * 128];
    __shared__ float ws[64 * 64];
    int t = threadIdx.x;
    int rowbase = blockIdx.x * 64;
    int colbase = blockIdx.y * 64;

    for (int p = 0; p < 8; ++p) {
        int i = t + p * 256;
        int r = i >> 5, q = i & 31;
        int nd = alive[rowbase + r];
        float g = gate[nd];
        float4 v = *(const float4*)(x + (size_t)nd * 128 + q * 4);
        v.x *= g; v.y *= g; v.z *= g; v.w *= g;
        *(float4*)(xs + r * 128 + q * 4) = v;
    }

    int c4 = (t & 15) * 4;
    int rb = (t >> 4) * 4;
    float4 a0 = {0, 0, 0, 0}, a1 = a0, a2 = a0, a3 = a0;

    for (int kh = 0; kh < 2; ++kh) {
        if (kh) __syncthreads();
        for (int p = 0; p < 4; ++p) {
            int i = t + p * 256;
            int kk = i >> 4, q = i & 15;
            *(float4*)(ws + kk * 64 + q * 4) =
                *(const float4*)(W + (size_t)(kh * 64 + kk) * 128 + colbase + q * 4);
        }
        __syncthreads();
        int kb = kh * 64;
        for (int k = 0; k < 64; k += 2) {
            float4 w0 = *(const float4*)(ws + k * 64 + c4);
            float4 w1 = *(const float4*)(ws + (k + 1) * 64 + c4);
            float2 x0 = *(const float2*)(xs + (rb + 0) * 128 + kb + k);
            float2 x1 = *(const float2*)(xs + (rb + 1) * 128 + kb + k);
            float2 x2 = *(const float2*)(xs + (rb + 2) * 128 + kb + k);
            float2 x3 = *(const float2*)(xs + (rb + 3) * 128 + kb + k);
            ACC4(a0, x0, w0, w1); ACC4(a1, x1, w0, w1);
            ACC4(a2, x2, w0, w1); ACC4(a3, x3, w0, w1);
        }
    }

    int n0 = alive[rowbase + rb + 0];
    int n1 = alive[rowbase + rb + 1];
    int n2 = alive[rowbase + rb + 2];
    int n3 = alive[rowbase + rb + 3];
    *(float4*)(h + (size_t)n0 * 128 + colbase + c4) = a0;
    *(float4*)(h + (size_t)n1 * 128 + colbase + c4) = a1;
    *(float4*)(h + (size_t)n2 * 128 + colbase + c4) = a2;
    *(float4*)(h + (size_t)n3 * 128 + colbase + c4) = a3;
}

// ---------------- agg v3: half-wave per dst row, L2 gather, compacted live neighbors ----
// Half-wave = 32 lanes x float4 = full 128-float row. One global_load_dwordx4 serves 2 edges/wave.
// Prefetch compacts the (<=16) live neighbors (id,weight) into LDS via ballot+popcount.
// Fused relu + final score (sigmoid((out.p)/||p||)) — half-wave owns the full row.
// XCD swizzle: blockIdx&127 = graph.

__global__ __launch_bounds__(256) void k_agg(const float* __restrict__ h, const float* __restrict__ dinv,
                                             const int* __restrict__ rp, const int* __restrict__ csr,
                                             const int* __restrict__ alive, const float* __restrict__ bias,
                                             const float* __restrict__ p, float* __restrict__ out,
                                             float* __restrict__ score, int Kp) {
    __shared__ float2 nb[8][16];
    int t = threadIdx.x;
    int slot = t >> 5;            // 0..7: dst slot within block
    int lane32 = t & 31;
    int half = slot & 1;
    int g = blockIdx.x & 127;
    int chunk = blockIdx.x >> 7;
    int idx = chunk * 8 + slot;

    int d = alive[g * Kp + idx];
    int jb = rp[d];
    int je = rp[d + 1];
    int deg = je - jb;

    // prefetch first min(16,deg) neighbors; compact live (w != 0) into nb[slot]
    int sid = 0; float wv = 0.f; bool livej = false;
    if (lane32 < 16 && lane32 < deg) {
        sid = csr[jb + lane32];
        wv = dinv[sid];
        livej = (wv != 0.f);
    }
    unsigned long long bal = __ballot(livej);
    unsigned hm = (unsigned)((bal >> (half * 32)) & 0xFFFFu);
    int cnt = __popc(hm);
    if (livej) {
        int pos = __popc(hm & ((1u << lane32) - 1));
        nb[slot][pos] = make_float2(wv, __int_as_float(sid));
    }
    // producer == consumer wave: no block barrier needed

    float dvd = dinv[d];
    float4 hd = *(const float4*)(h + (size_t)d * 128 + lane32 * 4);
    float4 a0, a1;
    a0.x = dvd * hd.x; a0.y = dvd * hd.y; a0.z = dvd * hd.z; a0.w = dvd * hd.w;
    a1.x = 0.f; a1.y = 0.f; a1.z = 0.f; a1.w = 0.f;

    int j = 0;
    for (; j + 2 <= cnt; j += 2) {
        float2 n0 = nb[slot][j];
        float2 n1 = nb[slot][j + 1];
        int s0 = __float_as_int(n0.y);
        int s1 = __float_as_int(n1.y);
        float4 h0 = *(const float4*)(h + (size_t)s0 * 128 + lane32 * 4);
        float4 h1 = *(const float4*)(h + (size_t)s1 * 128 + lane32 * 4);
        a0.x = fmaf(n0.x, h0.x, a0.x); a0.y = fmaf(n0.x, h0.y, a0.y);
        a0.z = fmaf(n0.x, h0.z, a0.z); a0.w = fmaf(n0.x, h0.w, a0.w);
        a1.x = fmaf(n1.x, h1.x, a1.x); a1.y = fmaf(n1.x, h1.y, a1.y);
        a1.z = fmaf(n1.x, h1.z, a1.z); a1.w = fmaf(n1.x, h1.w, a1.w);
    }
    if (j < cnt) {
        float2 n0 = nb[slot][j];
        int s0 = __float_as_int(n0.y);
        float4 h0 = *(const float4*)(h + (size_t)s0 * 128 + lane32 * 4);
        a0.x = fmaf(n0.x, h0.x, a0.x); a0.y = fmaf(n0.x, h0.y, a0.y);
        a0.z = fmaf(n0.x, h0.z, a0.z); a0.w = fmaf(n0.x, h0.w, a0.w);
    }
    for (int j2 = jb + 16; j2 < je; ++j2) {   // rare deg>16 tail
        int s2 = csr[j2];
        float w2 = dinv[s2];
        float4 h2 = *(const float4*)(h + (size_t)s2 * 128 + lane32 * 4);
        a0.x = fmaf(w2, h2.x, a0.x); a0.y = fmaf(w2, h2.y, a0.y);
        a0.z = fmaf(w2, h2.z, a0.z); a0.w = fmaf(w2, h2.w, a0.w);
    }

    float4 b4 = *(const float4*)(bias + lane32 * 4);
    float4 o;
    o.x = fmaxf(fmaf(dvd, a0.x + a1.x, b4.x), 0.f);
    o.y = fmaxf(fmaf(dvd, a0.y + a1.y, b4.y), 0.f);
    o.z = fmaxf(fmaf(dvd, a0.z + a1.z, b4.z), 0.f);
    o.w = fmaxf(fmaf(dvd, a0.w + a1.w, b4.w), 0.f);
    *(float4*)(out + (size_t)d * 128 + lane32 * 4) = o;

    float4 p4 = *(const float4*)(p + lane32 * 4);
    float ps = o.x * p4.x + o.y * p4.y + o.z * p4.z + o.w * p4.w;
    float q = p4.x * p4.x + p4.y * p4.y + p4.z * p4.z + p4.w * p4.w;
    for (int m = 16; m >= 1; m >>= 1) {
        ps += __shfl_xor(ps, m);
        q += __shfl_xor(q, m);
    }
    if (lane32 == 0) score[d] = 1.f / (1.f + expf(-ps * rsqrtf(q)));
}

// ---------------- fused: top-k + readout + next-layer dinv ----------------

__global__ __launch_bounds__(512) void k_pool(const float* __restrict__ xb, const float* __restrict__ score,
                                              float* __restrict__ gate, int* __restrict__ alive,
                                              float* __restrict__ hg, const int* __restrict__ rp,
                                              const int* __restrict__ csr, float* __restrict__ dinv,
                                              int K, int last) {
    __shared__ float s[512];
    __shared__ int ad[256];
    __shared__ float ag[256];
    __shared__ float red[1024];
    __shared__ int m_new[512];
    __shared__ int scnt;
    int t = threadIdx.x, g = blockIdx.x;
    int gbase = g * NPG;
    int d = gbase + t;

    float odv = dinv[d];
    int m = odv > 0.f;
    float sc = score[d];
    if (t == 0) scnt = 0;
    s[t] = m ? sc : -__builtin_inff();
    __syncthreads();
    for (int k2 = 2; k2 <= 512; k2 <<= 1)
        for (int j = k2 >> 1; j > 0; j >>= 1) {
            int ixj = t ^ j;
            if (ixj > t) {
                float a = s[t], bv = s[ixj];
                bool sw = ((t & k2) == 0) ? (a < bv) : (a > bv);
                if (sw) { s[t] = bv; s[ixj] = a; }
            }
            __syncthreads();
        }
    float thr = s[K - 1];
    int nm = (m && sc >= thr) ? 1 : 0;
    gate[d] = nm ? sc : 0.f;
    m_new[t] = nm;
    if (nm) {
        int pos = atomicAdd(&scnt, 1);
        if (pos < K) {
            alive[g * K + pos] = d;
            ad[pos] = d;
            ag[pos] = sc;
        }
    }
    __syncthreads();

    if (!last) {
        float nd = 0.f;
        if (nm) {
            int jb = rp[d], je = rp[d + 1];
            int sum = 0;
            for (int j = jb; j < je; ++j) sum += m_new[csr[j] - gbase];
            nd = rsqrtf(1.f + (float)sum);
        }
        dinv[d] = nd;
    }

    // readout on new alive set (values >= 0, outer relu identity); 4x unrolled gather
    int f = t & 127, c = t >> 7;
    float mx = 0.f, sm = 0.f;
    for (int j = c; j < K; j += 16) {
        float v0 = xb[(size_t)ad[j] * 128 + f] * ag[j];
        float v1 = xb[(size_t)ad[j + 4] * 128 + f] * ag[j + 4];
        float v2 = xb[(size_t)ad[j + 8] * 128 + f] * ag[j + 8];
        float v3 = xb[(size_t)ad[j + 12] * 128 + f] * ag[j + 12];
        mx = fmaxf(fmaxf(fmaxf(mx, v0), fmaxf(v1, v2)), v3);
        sm += v0 + v1 + v2 + v3;
    }
    red[t] = mx; red[512 + t] = sm;
    __syncthreads();
    if (c == 0) {
        for (int cc = 1; cc < 4; ++cc) {
            mx = fmaxf(mx, red[cc * 128 + f]);
            sm += red[512 + cc * 128 + f];
        }
        hg[g * 256 + f] += mx;
        hg[g * 256 + 128 + f] += sm / (float)K;
    }
}

// ---------------- fused MLP head ----------------

__global__ __launch_bounds__(256) void k_mlp(const float* __restrict__ inp_c, const float* __restrict__ hg,
                                             const float* __restrict__ We, const float* __restrict__ Wa,
                                             const float* __restrict__ ba, const float* __restrict__ Wb,
                                             const float* __restrict__ bb, const float* __restrict__ Wc,
                                             float* __restrict__ out) {
    __shared__ float fus[320];
    __shared__ float h1[256];
    __shared__ float h2[128];
    int t = threadIdx.x, g = blockIdx.x;
    if (t < 64) {
        float a = 0.f;
        for (int j = 0; j < 64; ++j) a = fmaf(inp_c[g * 64 + j], We[j * 64 + t], a);
        fus[t] = fmaxf(a, 0.f);
    }
    fus[64 + t] = hg[g * 256 + t];
    __syncthreads();
    {
        float a = ba[t];
        for (int j = 0; j < 320; ++j) a = fmaf(fus[j], Wa[j * 256 + t], a);
        h1[t] = fmaxf(a, 0.f);
    }
    __syncthreads();
    if (t < 128) {
        float a = bb[t];
        for (int j = 0; j < 256; ++j) a = fmaf(h1[j], Wb[j * 128 + t], a);
        h2[t] = fmaxf(a, 0.f);
    }
    __syncthreads();
    if (t == 0) {
        float a = 0.f;
        for (int j = 0; j < 128; ++j) a = fmaf(h2[j], Wc[j], a);
        out[g] = a;
    }
}

// ---------------- launch ----------------

extern "C" void kernel_launch(void* const* d_in, const int* in_sizes, int n_in,
                              void* d_out, int out_size, void* d_ws, size_t ws_size,
                              hipStream_t stream) {
    (void)in_sizes; (void)n_in; (void)out_size; (void)ws_size;
    const float* x_in  = (const float*)d_in[0];
    const float* inp_c = (const float*)d_in[1];
    const int*   ei    = (const int*)d_in[2];
    const int* srcE = ei;
    const int* dstE = ei + NEDGE;
    const float* Wl[3] = {(const float*)d_in[4], (const float*)d_in[6], (const float*)d_in[8]};
    const float* bl[3] = {(const float*)d_in[5], (const float*)d_in[7], (const float*)d_in[9]};
    const float* Pl[3] = {(const float*)d_in[10], (const float*)d_in[11], (const float*)d_in[12]};
    const float* We = (const float*)d_in[13];
    const float* Wa = (const float*)d_in[14];
    const float* ba = (const float*)d_in[15];
    const float* Wb = (const float*)d_in[16];
    const float* bb = (const float*)d_in[17];
    const float* Wc = (const float*)d_in[18];
    float* out = (float*)d_out;

    char* w = (char*)d_ws;
    size_t off = 0;
    auto alloc = [&](size_t bytes) -> void* {
        void* p = w + off;
        off = (off + bytes + 255) & ~(size_t)255;
        return p;
    };
    int*   rp    = (int*)alloc((NNODE + 1) * 4);
    int*   csr   = (int*)alloc(NEDGE * 4);
    float* dinv  = (float*)alloc(NNODE * 4);
    float* gate  = (float*)alloc(NNODE * 4);
    float* score = (float*)alloc(NNODE * 4);
    int*   alive = (int*)alloc(NNODE * 4);
    float* hbuf  = (float*)alloc((size_t)NNODE * 128 * 4);
    float* xbuf  = (float*)alloc((size_t)NNODE * 128 * 4);
    float* hg    = (float*)alloc(NGRAPH * 256 * 4);

    hipMemsetAsync(hg, 0, NGRAPH * 256 * 4, stream);
    k_csr<<<NGRAPH, 512, 0, stream>>>(srcE, dstE, rp, csr, gate, alive, dinv);

    const int rows_in[3] = {65536, 32768, 16384};
    const int Ks[3] = {256, 128, 64};
    const int Kp[3] = {512, 256, 128};   // alive-list stride entering layer l
    for (int l = 0; l < 3; ++l) {
        const float* xin = (l == 0) ? x_in : xbuf;
        k_gemm<<<dim3(rows_in[l] / 64, 2), 256, 0, stream>>>(xin, Wl[l], gate, alive, hbuf);
        k_agg<<<rows_in[l] / 8 * 16 / 16, 256, 0, stream>>>(hbuf, dinv, rp, csr, alive, bl[l], Pl[l],
                                                            xbuf, score, Kp[l]);
        k_pool<<<NGRAPH, 512, 0, stream>>>(xbuf, score, gate, alive, hg,
                                           rp, csr, dinv, Ks[l], l == 2);
    }
    k_mlp<<<NGRAPH, 256, 0, stream>>>(inp_c, hg, We, Wa, ba, Wb, bb, Wc, out);
}